// Round 4
// baseline (223.728 us; speedup 1.0000x reference)
//
#include <hip/hip_runtime.h>
#include <stdint.h>

// ProposalLayerSoft: 3x3x3 NMS + per-batch top-10 + coord epilogue.
// Input:  d_in[0] = root_cubes f32 [B=32, X=128, Y=128, Z=64]
// Output: d_out   = f32 [B, 10, 5] = (x,y,z, valid-1, score)
// ws: part = B*40*10*8 bytes of per-block top-10 keys, then cnt[B] u32.
//
// THRESHOLD FAST PATH (round 4). Evidence r0-r3: kernel is NOT bound by
// VALU (36%), HBM BW (14%), LDS (0 conflicts), or load latency (r2
// no-prefetch == r3 prefetch == 81us). Per-j-iter stall ~600-900cy,
// invariant across layouts: the per-voxel emission pipeline (27-max +
// wave-wide ballot + mbcnt + exec-branch + LDS append per 512 voxels)
// is the cost. Fix: gate on v > T (T=0.999). Top-10 of ~38.8k peaks
// per batch all have v ~ 1; E[peaks>T] ~ 1035 +- 32 >> 10.
// EXACTNESS: if >=10 peaks have v>T, the 10th-best peak >T, so the
// thresholded emission contains the true top-10 bitwise. Pass 1 counts
// peaks>T per batch (atomicAdd); pass 2 = same kernel, T off, early-
// exits when cnt[b]>=10 (never fires on bench input, full dense NMS if
// it does). Main loop now: load plane, max8+1 cmp+1 ballot per t-iter
// (64% of t-iters skip everything), 3 raw-plane rotate. 27-max computed
// on demand from raw planes vP/vC/vN only for gated j's (~5%).
//   z: stripe max3 from regs; edges via lane+-16 bpermute / halo scalar.
//   y: v_mov_dpp row_shl/shr:1 on xm (all lanes compute xm -> DPP valid).
//   x: rolled 16-step sweep, 3-plane rotate, load vN at iter bottom.
// __launch_bounds__(256,5): cap 48 VGPR. r1: bound 6 = cap 40 spills
// 580MB scratch. DO NOT raise. Carried: 24 plane + 6 halo + temps ~44.
// Grid (TY,4,B): 1280 blocks = 5/CU exactly, single phase.

#define TPB 256
#define NK 10
#define TY 10                    // y tiles, 14 interior columns each
#define BLOCKS_PER_B (4 * TY)    // grid.y=4 packs x 10 ty = 40
#define WCAP 512                 // per-wave cand cap (fallback: mean ~265)
#define THRV 0.999f              // pass-1 value gate; exact given cnt>=10
typedef unsigned long long u64;

__device__ __forceinline__ u64 bfly_max_u64(u64 v) {
#pragma unroll
  for (int off = 1; off < 64; off <<= 1) {
    u64 o = __shfl_xor(v, off, 64);
    v = (o > v) ? o : v;
  }
  return v;
}

// DPP row shifts within 16-lane rows; bound_ctrl=1 -> 0.0f fill at row
// edges (only yi=0/15 halo lanes, never emitted).
__device__ __forceinline__ float dpp_nbr_a(float v) {  // one y-neighbor
  return __int_as_float(__builtin_amdgcn_update_dpp(
      0, __float_as_int(v), 0x101, 0xF, 0xF, true));   // row_shl:1
}
__device__ __forceinline__ float dpp_nbr_b(float v) {  // other y-neighbor
  return __int_as_float(__builtin_amdgcn_update_dpp(
      0, __float_as_int(v), 0x111, 0xF, 0xF, true));   // row_shr:1
}

template <bool PASS1>
__global__ __launch_bounds__(TPB, 5) void peaks_topk(
    const float* __restrict__ in, u64* __restrict__ part,
    unsigned* __restrict__ cnt) {
  __shared__ u64 cand[4][WCAP];  // 16 KB
  __shared__ u64 wtop[4 * NK];
  __shared__ unsigned wcnts[4];
  const int b = blockIdx.z;
  if (!PASS1) {
    if (cnt[b] >= NK) return;    // fallback not needed for this batch
  }
  const int tid = threadIdx.x;
  const int w = tid >> 6, lane = tid & 63;
  const int yi = lane & 15, zq = lane >> 4;
  const int ty = blockIdx.x;
  const int seg = blockIdx.y * 2 + (w >> 1);  // 0..7, 16 x-steps each
  const int zh = w & 1;                       // z half: 0 -> 0..31, 1 -> 32..63
  const int y0 = ty * 14 - 1;
  const int gy = y0 + yi;
  const int cy = min(127, max(0, gy));        // clamp == dup col: max-safe
  const int x0 = seg << 4;
  const bool emit_ok = (yi >= 1) && (yi <= 14) && (gy <= 127);
  const int zoff = zh * 32 + (zq << 3);       // lane's z base in column
  const int zlo = max(0, zoff - 1);           // cross-wave z halo offsets
  const int zhi = min(63, zoff + 8);
  const bool lo_inf = (zq == 0) && (zh == 0); // z = -1
  const bool hi_inf = (zq == 3) && (zh == 1); // z = 64
  const float* __restrict__ py = in + ((size_t)b << 20) + ((size_t)cy << 6);

  int wcnt = 0;  // wave-uniform emitted-peak count (scalar, uncapped)
  float vP[8], vC[8], vN[8];
  float loP, hiP, loC, hiC, loN, hiN;

  auto loadv = [&](int x, float* v, float& lo, float& hi) {
    const int cx = min(127, max(0, x));       // x clamp = dup plane: max-safe
    const float* p = py + ((size_t)cx << 13);
    float4 a = *(const float4*)(p + zoff);
    float4 bb = *(const float4*)(p + zoff + 4);
    v[0] = a.x;  v[1] = a.y;  v[2] = a.z;  v[3] = a.w;
    v[4] = bb.x; v[5] = bb.y; v[6] = bb.z; v[7] = bb.w;
    lo = p[zlo];                              // used by zq==0 lanes
    hi = p[zhi];                              // used by zq==3 lanes
  };

  loadv(x0 - 1, vP, loP, hiP);
  loadv(x0,     vC, loC, hiC);
  loadv(x0 + 1, vN, loN, hiN);

#pragma unroll 1
  for (int t = 0; t < 16; ++t) {
    const int x = x0 + t;
    bool anyc;
    if (PASS1) {
      float cm = fmaxf(fmaxf(fmaxf(vC[0], vC[1]), fmaxf(vC[2], vC[3])),
                       fmaxf(fmaxf(vC[4], vC[5]), fmaxf(vC[6], vC[7])));
      anyc = emit_ok && (cm > THRV);
    } else {
      anyc = emit_ok;
    }
    if (__ballot(anyc)) {        // wave-uniform: all lanes enter
      // z-stripe edge values for the 3 planes (shuffle in-wave, halo else)
      float vlP = __shfl_up(vP[7], 16, 64), vrP = __shfl_down(vP[0], 16, 64);
      float vlC = __shfl_up(vC[7], 16, 64), vrC = __shfl_down(vC[0], 16, 64);
      float vlN = __shfl_up(vN[7], 16, 64), vrN = __shfl_down(vN[0], 16, 64);
      vlP = (zq == 0) ? (lo_inf ? -1e30f : loP) : vlP;
      vrP = (zq == 3) ? (hi_inf ? -1e30f : hiP) : vrP;
      vlC = (zq == 0) ? (lo_inf ? -1e30f : loC) : vlC;
      vrC = (zq == 3) ? (hi_inf ? -1e30f : hiC) : vrC;
      vlN = (zq == 0) ? (lo_inf ? -1e30f : loN) : vlN;
      vrN = (zq == 3) ? (hi_inf ? -1e30f : hiN) : vrN;
#pragma unroll
      for (int j = 0; j < 8; ++j) {
        const float v = vC[j];
        const bool pj = emit_ok && (PASS1 ? (v > THRV) : true);
        if (__ballot(pj)) {      // wave-uniform; all lanes compute xm (DPP)
          float aP = (j == 0) ? vlP : vP[j - 1];
          float cP = (j == 7) ? vrP : vP[j + 1];
          float aC = (j == 0) ? vlC : vC[j - 1];
          float cC = (j == 7) ? vrC : vC[j + 1];
          float aN = (j == 0) ? vlN : vN[j - 1];
          float cN = (j == 7) ? vrN : vN[j + 1];
          float zP = fmaxf(aP, fmaxf(vP[j], cP));
          float zC = fmaxf(aC, fmaxf(v, cC));
          float zN = fmaxf(aN, fmaxf(vN[j], cN));
          float xm = fmaxf(zP, fmaxf(zC, zN));
          float l = dpp_nbr_a(xm);           // y-neighbors via DPP
          float r = dpp_nbr_b(xm);
          float m27 = fmaxf(xm, fmaxf(l, r));
          const bool pred = pj && (v >= m27);  // v == 27-max (self-incl.)
          u64 mask = __ballot(pred);
          if (pred) {
            unsigned g = ((unsigned)x << 13) | ((unsigned)gy << 6) |
                         (unsigned)(zoff + j);
            u64 key = ((u64)__float_as_uint(v) << 32) | (u64)(unsigned)(~g);
            int ofs = __builtin_amdgcn_mbcnt_hi(
                (unsigned)(mask >> 32),
                __builtin_amdgcn_mbcnt_lo((unsigned)mask, 0));
            int slot = wcnt + ofs;
            if (slot < WCAP) cand[w][slot] = key;
          }
          wcnt += (int)__popcll(mask);
        }
      }
    }
    // rotate raw planes + halos; load plane x+2 into vN (clamped: tail-safe)
#pragma unroll
    for (int j = 0; j < 8; ++j) {
      vP[j] = vC[j];
      vC[j] = vN[j];
    }
    loP = loC; hiP = hiC; loC = loN; hiC = hiN;
    loadv(x + 2, vN, loN, hiN);
  }

  // ---- wave top-10 from LDS list (regs + butterfly, no barriers) ----
  __builtin_amdgcn_s_waitcnt(0);  // drain own-wave LDS writes
  const int count = min(wcnt, WCAP);
  u64 c[WCAP / 64];
#pragma unroll
  for (int i = 0; i < WCAP / 64; ++i) {
    int idx = lane + (i << 6);
    c[i] = (idx < count) ? cand[w][idx] : 0;
  }
  u64 mine = 0;
#pragma unroll 1
  for (int r = 0; r < NK; ++r) {
    u64 best = c[0];
#pragma unroll
    for (int i = 1; i < WCAP / 64; ++i) best = (c[i] > best) ? c[i] : best;
    u64 m = bfly_max_u64(best);
    if (m != 0 && best == m) {  // unique keys: only owner lane matches
#pragma unroll
      for (int i = 0; i < WCAP / 64; ++i)
        if (c[i] == m) c[i] = 0;
    }
    if (lane == r) mine = m;
  }
  if (lane < NK) wtop[w * NK + lane] = mine;
  if (lane == 0) wcnts[w] = (unsigned)wcnt;
  __syncthreads();

  // ---- block merge 40 -> 10 (wave 0), one barrier total ----
  if (w == 0) {
    u64 c0 = (lane < 4 * NK) ? wtop[lane] : 0;
    u64 mv = 0;
#pragma unroll 1
    for (int r = 0; r < NK; ++r) {
      u64 m = bfly_max_u64(c0);
      if (m != 0 && c0 == m) c0 = 0;
      if (lane == r) mv = m;
    }
    if (lane < NK) {
      const int bi = blockIdx.y * TY + ty;  // 0..39 within batch
      part[((size_t)b * BLOCKS_PER_B + bi) * NK + lane] = mv;
    }
    if (PASS1 && lane == 0) {
      unsigned s = wcnts[0] + wcnts[1] + wcnts[2] + wcnts[3];
      if (s) atomicAdd(&cnt[b], s);  // peaks with v > THRV in this block
    }
  }
}

// One wave per batch: 400 keys -> 7 regs/lane -> 10 butterfly rounds.
// Zero barriers, zero LDS.
__global__ __launch_bounds__(64) void final_select(
    const u64* __restrict__ part, float* __restrict__ out) {
  const int lane = threadIdx.x & 63;
  const int b = blockIdx.x;
  const int NKEY = BLOCKS_PER_B * NK;  // 400

  const u64* __restrict__ src = part + (size_t)b * NKEY;
  u64 c[7];
#pragma unroll
  for (int i = 0; i < 7; ++i) {
    int idx = lane + (i << 6);
    c[i] = (idx < NKEY) ? src[idx] : 0;
  }
  u64 mine = 0;
#pragma unroll 1
  for (int r = 0; r < NK; ++r) {
    u64 best = c[0];
#pragma unroll
    for (int i = 1; i < 7; ++i) best = (c[i] > best) ? c[i] : best;
    u64 m = bfly_max_u64(best);
    if (m != 0 && best == m) {
#pragma unroll
      for (int i = 0; i < 7; ++i)
        if (c[i] == m) c[i] = 0;
    }
    if (lane == r) mine = m;
  }
  if (lane < NK) {
    float val = 0.0f;
    unsigned g = 0u;
    if (mine != 0) {
      val = __uint_as_float((unsigned)(mine >> 32));
      g = ~((unsigned)mine);
    }
    float fx = (float)(g >> 13) * (8000.0f / 127.0f) - 4000.0f;
    float fy = (float)((g >> 6) & 127u) * (8000.0f / 127.0f) - 4000.0f;
    float fz = (float)(g & 63u) * (2000.0f / 63.0f) - 700.0f;
    float conf = (val > 0.3f) ? 0.0f : -1.0f;
    float* o = out + ((size_t)b * NK + lane) * 5;
    o[0] = fx; o[1] = fy; o[2] = fz; o[3] = conf; o[4] = val;
  }
}

extern "C" void kernel_launch(void* const* d_in, const int* in_sizes, int n_in,
                              void* d_out, int out_size, void* d_ws, size_t ws_size,
                              hipStream_t stream) {
  const float* in = (const float*)d_in[0];
  float* out = (float*)d_out;
  u64* part = (u64*)d_ws;
  const int B = in_sizes[0] >> 20;  // 128*128*64 = 2^20 elements per batch
  unsigned* cnt =
      (unsigned*)((char*)d_ws + (size_t)B * BLOCKS_PER_B * NK * sizeof(u64));

  hipMemsetAsync(cnt, 0, (size_t)B * sizeof(unsigned), stream);
  dim3 gridA(TY, 4, (unsigned)B);
  peaks_topk<true><<<gridA, dim3(TPB), 0, stream>>>(in, part, cnt);
  // Fallback: exact dense NMS for any batch with <10 peaks above THRV.
  // Early-exits per block on the bench distribution (cnt ~ 1035 >> 10).
  peaks_topk<false><<<gridA, dim3(TPB), 0, stream>>>(in, part, cnt);
  final_select<<<dim3((unsigned)B), dim3(64), 0, stream>>>(part, out);
}